// Round 1
// baseline (726.312 us; speedup 1.0000x reference)
//
#include <hip/hip_runtime.h>

// BlkQ4Linear: out[m,n] = sum_k in[m,k]*(q[n,k]-zp[n,k/64])*s[n,k/64] + bias[n]
// M=4096 K=4096 N=11008.
// Round 4: replace the 128x128 2-barrier GEMM (m97 structure, measured 52%
// MfmaUtil / ~1055 TF) with the 256x256 8-phase counted-vmcnt schedule
// (T3+T4+T5). Two K-tiles double-buffered in 128 KiB LDS; each phase =
// {12-or-4 ds_read_b128, stage one half-tile via 2x global_load_lds_dwordx4,
// barrier, 16 MFMA under setprio, counted vmcnt, barrier}. vmcnt never
// drains to 0 in the main loop (vmcnt(8) at phases 4/8, vmcnt(6) at 1/5);
// 3-4 half-tiles stay in flight across barriers. Zero-conflict
// chunk^(row&7) LDS swizzle kept from R3 (pre-swizzled global source,
// linear LDS dest as global_load_lds requires).

#define BM 128
#define BN 128
#define BK 64
#define LDSN 72  // fused-fallback LDS pad

typedef __attribute__((ext_vector_type(8))) short bf16x8;
typedef __attribute__((ext_vector_type(4))) float f32x4;

__device__ __forceinline__ unsigned short f2bf(float f) {
    union { float f; unsigned int u; } v; v.f = f;
    unsigned int u = v.u;
    u += 0x7FFFu + ((u >> 16) & 1u);   // RNE
    return (unsigned short)(u >> 16);
}
__device__ __forceinline__ unsigned int pack2(float a, float b) {
    return (unsigned int)f2bf(a) | ((unsigned int)f2bf(b) << 16);
}

__device__ __forceinline__ void gl_lds16(const void* gp, void* lp) {
    __builtin_amdgcn_global_load_lds(
        (const __attribute__((address_space(1))) unsigned int*)gp,
        (__attribute__((address_space(3))) unsigned int*)lp,
        16, 0, 0);
}

// ---------------- Pass 1a: A fp32 -> bf16 ----------------
__global__ __launch_bounds__(256)
void a2bf_kernel(const float* __restrict__ A, unsigned short* __restrict__ Ab,
                 long total4)
{
    long t = (long)blockIdx.x * blockDim.x + threadIdx.x;
    if (t >= total4) return;
    float4 v = ((const float4*)A)[t];
    uint2 p; p.x = pack2(v.x, v.y); p.y = pack2(v.z, v.w);
    ((uint2*)Ab)[t] = p;
}

// ---------------- Pass 1b: Q int32 codes -> bf16 W ----------------
__global__ __launch_bounds__(256)
void dequant_kernel(const int* __restrict__ Q, const float* __restrict__ S,
                    const int* __restrict__ Zp, unsigned short* __restrict__ W,
                    int K, int nb)
{
    const int n = blockIdx.y;
    const int k = (blockIdx.x * 256 + threadIdx.x) * 8;
    if (k >= K) return;
    const int kb = k >> 6;
    const float s  = S[(size_t)n * nb + kb];
    const float zs = (float)Zp[(size_t)n * nb + kb] * s;
    const int4* qp = (const int4*)(Q + (size_t)n * K + k);
    int4 q0 = qp[0], q1 = qp[1];
    uint4 o;
    o.x = pack2((float)q0.x * s - zs, (float)q0.y * s - zs);
    o.y = pack2((float)q0.z * s - zs, (float)q0.w * s - zs);
    o.z = pack2((float)q1.x * s - zs, (float)q1.y * s - zs);
    o.w = pack2((float)q1.z * s - zs, (float)q1.w * s - zs);
    *(uint4*)(W + (size_t)n * K + k) = o;
}

// ---------------- Pass 2 (new): 256x256 8-phase bf16 GEMM ----------------
// Waves 2(M) x 4(N); per-wave 128x64 C. Phase quadrant (mh,nh) = 128x128 of
// the block tile; per wave per phase: 4 m-frags x 2 n-frags x 2 ks = 16 MFMA.
// LDS: As[2][256][64], Bs[2][256][64] bf16 (128 KiB). Tile t -> buf[t&1].
// Half-tile = 128 rows x 64 cols of one matrix = 1024 16B chunks = 2
// global_load_lds per thread. Swizzle: physical chunk p of row r holds
// logical chunk p^(r&7); applied on the global source column at staging and
// inverted in the ds_read address (measured 0 bank-conflict cycles in R3).

#define G8_BARRIER() do { asm volatile("" ::: "memory");                    \
    __builtin_amdgcn_s_barrier(); asm volatile("" ::: "memory"); } while (0)
#define G8_VMCNT(n) asm volatile("s_waitcnt vmcnt(" #n ")" ::: "memory")
#define G8_LGKM0()  do { asm volatile("s_waitcnt lgkmcnt(0)" ::: "memory"); \
    __builtin_amdgcn_sched_barrier(0); } while (0)

// stage one half-tile: matrix base G (block-row pre-offset), k-tile kt,
// half h (0: rows 0-127, 1: rows 128-255), LDS matrix base, buffer b
#define G8_STAGE(G, kt, h, base, b)                                          \
  do {                                                                       \
    const unsigned short* _s = (G) + (long)(kt) * 64 + (long)(h) * 128 * K;  \
    gl_lds16(_s + aoff0, (base) + (b) * 32768 + (h) * 16384 + lds0);         \
    gl_lds16(_s + aoff1, (base) + (b) * 32768 + (h) * 16384 + lds1);         \
  } while (0)

#define G8_LOAD_AF(b, mh)                                                    \
  { _Pragma("unroll") for (int _i = 0; _i < 4; ++_i) {                       \
      const int _ra = (mh) * 128 + arow + _i * 16;                           \
      const char* _pa = AsB + (b) * 32768 + _ra * 128;                       \
      af[_i][0] = *(const bf16x8*)(_pa + ck0);                               \
      af[_i][1] = *(const bf16x8*)(_pa + ck1);                               \
  } }

#define G8_LOAD_BF(b, nh)                                                    \
  { _Pragma("unroll") for (int _j = 0; _j < 2; ++_j) {                       \
      const int _rb = (nh) * 128 + brow + _j * 16;                           \
      const char* _pb = BsB + (b) * 32768 + _rb * 128;                       \
      bfg[_j][0] = *(const bf16x8*)(_pb + ck0);                              \
      bfg[_j][1] = *(const bf16x8*)(_pb + ck1);                              \
  } }

#define G8_MFMA(q)                                                           \
  __builtin_amdgcn_s_setprio(1);                                             \
  { _Pragma("unroll") for (int _i = 0; _i < 4; ++_i)                         \
    _Pragma("unroll") for (int _j = 0; _j < 2; ++_j) {                       \
      acc[q][_i][_j] = __builtin_amdgcn_mfma_f32_16x16x32_bf16(              \
          af[_i][0], bfg[_j][0], acc[q][_i][_j], 0, 0, 0);                   \
      acc[q][_i][_j] = __builtin_amdgcn_mfma_f32_16x16x32_bf16(              \
          af[_i][1], bfg[_j][1], acc[q][_i][_j], 0, 0, 0);                   \
  } }                                                                        \
  __builtin_amdgcn_s_setprio(0);

__global__ __launch_bounds__(512, 2)
void gemm8_kernel(const unsigned short* __restrict__ Ab,
                  const unsigned short* __restrict__ Wb,
                  const float* __restrict__ bias, float* __restrict__ C,
                  int M, int N, int K)
{
    __shared__ __align__(16) unsigned short As[2][256][64];
    __shared__ __align__(16) unsigned short Bs[2][256][64];

    const int tid  = threadIdx.x;
    const int m0   = blockIdx.x * 256;
    const int n0   = blockIdx.y * 256;
    const int lane = tid & 63;
    const int wave = tid >> 6;
    const int ww   = wave >> 2;       // 0..1, m-dir within quadrant
    const int wv   = wave & 3;        // 0..3, n-dir
    const int fr   = lane & 15;
    const int quad = lane >> 4;
    const int sw   = fr & 7;

    // staging constants: thread covers chunks tid and 512+tid of each half
    const int rl0 = tid >> 3;          // local row 0..63
    const int rl1 = (512 + tid) >> 3;  // local row 64..127
    const int pp  = tid & 7;           // physical chunk in row
    const long aoff0 = (long)rl0 * K + (long)((pp ^ (rl0 & 7)) * 8);
    const long aoff1 = (long)rl1 * K + (long)((pp ^ (rl1 & 7)) * 8);
    const int lds0 = tid * 16;
    const int lds1 = (512 + tid) * 16;

    // fragment-read constants (inverse swizzle): logical chunk l=ks*4+quad
    const int ck0 = (quad ^ sw) * 16;
    const int ck1 = ((4 + quad) ^ sw) * 16;
    const int arow = ww * 64 + fr;
    const int brow = wv * 32 + fr;

    char* AsB = (char*)&As[0][0][0];
    char* BsB = (char*)&Bs[0][0][0];

    const unsigned short* Ag = Ab + (size_t)m0 * K;
    const unsigned short* Bg = Wb + (size_t)n0 * K;

    f32x4 acc[4][4][2];
    #pragma unroll
    for (int q = 0; q < 4; ++q)
        #pragma unroll
        for (int i = 0; i < 4; ++i)
            #pragma unroll
            for (int j = 0; j < 2; ++j)
                acc[q][i][j] = (f32x4){0.f, 0.f, 0.f, 0.f};

    bf16x8 af[4][2], bfg[2][2];

    // ---- prologue: tile0 (buf0) fully + A0,B0 of tile1 (buf1) ----
    G8_STAGE(Ag, 0, 0, AsB, 0);
    G8_STAGE(Bg, 0, 0, BsB, 0);
    G8_STAGE(Ag, 0, 1, AsB, 0);
    G8_STAGE(Bg, 0, 1, BsB, 0);
    G8_STAGE(Ag, 1, 0, AsB, 1);
    G8_STAGE(Bg, 1, 0, BsB, 1);
    G8_VMCNT(4);              // tile0's 8 loads landed; 2 ht in flight
    G8_BARRIER();

    const int nit = K / 128;  // iterations of 2 K-tiles
    for (int it = 0; it < nit - 1; ++it) {
        const int t = 2 * it;
        // P1: buf0 q(0,0) | stage A1(t+1)->As1 | vmcnt(6)
        G8_LOAD_AF(0, 0); G8_LOAD_BF(0, 0);
        G8_STAGE(Ag, t + 1, 1, AsB, 1);
        G8_BARRIER(); G8_LGKM0();
        G8_MFMA(0);
        G8_VMCNT(6);
        G8_BARRIER();
        // P2: buf0 q(0,1) | stage B1(t+1)->Bs1
        G8_LOAD_BF(0, 1);
        G8_STAGE(Bg, t + 1, 1, BsB, 1);
        G8_BARRIER(); G8_LGKM0();
        G8_MFMA(1);
        G8_BARRIER();
        // P3: buf0 q(1,0) | stage A0(t+2)->As0 (A0 slot freed after P1 reads)
        G8_LOAD_AF(0, 1); G8_LOAD_BF(0, 0);
        G8_STAGE(Ag, t + 2, 0, AsB, 0);
        G8_BARRIER(); G8_LGKM0();
        G8_MFMA(2);
        G8_BARRIER();
        // P4: buf0 q(1,1) | stage B0(t+2)->Bs0 | vmcnt(8)
        G8_LOAD_BF(0, 1);
        G8_STAGE(Bg, t + 2, 0, BsB, 0);
        G8_BARRIER(); G8_LGKM0();
        G8_MFMA(3);
        G8_VMCNT(8);           // guards A0,B0(t+1) for P5
        G8_BARRIER();
        // P5: buf1 q(0,0) | stage A1(t+2)->As0 | vmcnt(6)
        G8_LOAD_AF(1, 0); G8_LOAD_BF(1, 0);
        G8_STAGE(Ag, t + 2, 1, AsB, 0);
        G8_BARRIER(); G8_LGKM0();
        G8_MFMA(0);
        G8_VMCNT(6);           // guards B1(t+1) for P6, A1(t+1) for P7
        G8_BARRIER();
        // P6: buf1 q(0,1) | stage B1(t+2)->Bs0
        G8_LOAD_BF(1, 1);
        G8_STAGE(Bg, t + 2, 1, BsB, 0);
        G8_BARRIER(); G8_LGKM0();
        G8_MFMA(1);
        G8_BARRIER();
        // P7: buf1 q(1,0) | stage A0(t+3)->As1
        G8_LOAD_AF(1, 1); G8_LOAD_BF(1, 0);
        G8_STAGE(Ag, t + 3, 0, AsB, 1);
        G8_BARRIER(); G8_LGKM0();
        G8_MFMA(2);
        G8_BARRIER();
        // P8: buf1 q(1,1) | stage B0(t+3)->Bs1 | vmcnt(8)
        G8_LOAD_BF(1, 1);
        G8_STAGE(Bg, t + 3, 0, BsB, 1);
        G8_BARRIER(); G8_LGKM0();
        G8_MFMA(3);
        G8_VMCNT(8);           // guards A0,B0(t+2) for next P1
        G8_BARRIER();
    }
    // ---- peeled last iteration (tiles K/64-2, K/64-1): drain 4->0 ----
    {
        const int t = 2 * (nit - 1);
        G8_LOAD_AF(0, 0); G8_LOAD_BF(0, 0);
        G8_STAGE(Ag, t + 1, 1, AsB, 1);
        G8_BARRIER(); G8_LGKM0(); G8_MFMA(0); G8_VMCNT(6); G8_BARRIER();

        G8_LOAD_BF(0, 1);
        G8_STAGE(Bg, t + 1, 1, BsB, 1);
        G8_BARRIER(); G8_LGKM0(); G8_MFMA(1); G8_BARRIER();

        G8_LOAD_AF(0, 1); G8_LOAD_BF(0, 0);
        G8_BARRIER(); G8_LGKM0(); G8_MFMA(2); G8_BARRIER();

        G8_LOAD_BF(0, 1);
        G8_BARRIER(); G8_LGKM0(); G8_MFMA(3); G8_VMCNT(4); G8_BARRIER();

        G8_LOAD_AF(1, 0); G8_LOAD_BF(1, 0);
        G8_BARRIER(); G8_LGKM0(); G8_MFMA(0); G8_VMCNT(0); G8_BARRIER();

        G8_LOAD_BF(1, 1);
        G8_BARRIER(); G8_LGKM0(); G8_MFMA(1); G8_BARRIER();

        G8_LOAD_AF(1, 1); G8_LOAD_BF(1, 0);
        G8_BARRIER(); G8_LGKM0(); G8_MFMA(2); G8_BARRIER();

        G8_LOAD_BF(1, 1);
        G8_BARRIER(); G8_LGKM0(); G8_MFMA(3); G8_BARRIER();
    }

    // ---- epilogue: D layout col = fr (n), row = quad*4 + r (m) ----
    #pragma unroll
    for (int q = 0; q < 4; ++q) {
        const int mh = q >> 1, nh = q & 1;
        #pragma unroll
        for (int j = 0; j < 2; ++j) {
            const int n = n0 + nh * 128 + brow + j * 16;
            const float bv = bias[n];
            #pragma unroll
            for (int i = 0; i < 4; ++i) {
                const int mb = m0 + mh * 128 + ww * 64 + i * 16 + quad * 4;
                #pragma unroll
                for (int r = 0; r < 4; ++r)
                    C[(size_t)(mb + r) * N + n] = acc[q][i][j][r] + bv;
            }
        }
    }
}

// ---------------- Pass 2 (fallback): 128x128 m97-structure GEMM ----------------
__global__ __launch_bounds__(256, 2)
void gemm_bt_kernel(const unsigned short* __restrict__ Ab,
                    const unsigned short* __restrict__ Wb,
                    const float* __restrict__ bias, float* __restrict__ C,
                    int M, int N, int K)
{
    __shared__ __align__(16) unsigned short As[BM * BK];
    __shared__ __align__(16) unsigned short Bs[BN * BK];

    const int tid = threadIdx.x;
    const int m0  = blockIdx.x * BM;
    const int n0  = blockIdx.y * BN;

    const int lane = tid & 63;
    const int wave = tid >> 6;
    const int wm   = (wave >> 1) * 64;
    const int wn   = (wave & 1) * 64;
    const int fr   = lane & 15;
    const int quad = lane >> 4;
    const int sw   = fr & 7;

    f32x4 acc[4][4];
    #pragma unroll
    for (int i = 0; i < 4; ++i)
        #pragma unroll
        for (int j = 0; j < 4; ++j)
            acc[i][j] = (f32x4){0.f, 0.f, 0.f, 0.f};

    const int ktiles = K / BK;
    for (int kt = 0; kt < ktiles; ++kt) {
        const int k0 = kt * BK;
        #pragma unroll
        for (int i = 0; i < 4; ++i) {
            const int c    = i * 256 + tid;
            const int row  = c >> 3;
            const int g    = (c & 7) ^ (row & 7);
            const int cole = g * 8;
            gl_lds16(Ab + (size_t)(m0 + row) * K + k0 + cole, (char*)As + c * 16);
            gl_lds16(Wb + (size_t)(n0 + row) * K + k0 + cole, (char*)Bs + c * 16);
        }
        __syncthreads();

        #pragma unroll
        for (int ks = 0; ks < 2; ++ks) {
            bf16x8 af[4], bfg[4];
            #pragma unroll
            for (int i = 0; i < 4; ++i) {
                const int row = wm + i * 16 + fr;
                const int p   = (ks * 4 + quad) ^ sw;
                af[i] = *(const bf16x8*)&As[row * BK + p * 8];
            }
            #pragma unroll
            for (int j = 0; j < 4; ++j) {
                const int row = wn + j * 16 + fr;
                const int p   = (ks * 4 + quad) ^ sw;
                bfg[j] = *(const bf16x8*)&Bs[row * BK + p * 8];
            }
            #pragma unroll
            for (int i = 0; i < 4; ++i)
                #pragma unroll
                for (int j = 0; j < 4; ++j)
                    acc[i][j] = __builtin_amdgcn_mfma_f32_16x16x32_bf16(af[i], bfg[j], acc[i][j], 0, 0, 0);
        }
        __syncthreads();
    }

    #pragma unroll
    for (int j = 0; j < 4; ++j) {
        const int n = n0 + wn + j * 16 + fr;
        const float bv = bias[n];
        #pragma unroll
        for (int i = 0; i < 4; ++i) {
            const int mb = m0 + wm + i * 16 + quad * 4;
            #pragma unroll
            for (int r = 0; r < 4; ++r)
                C[(size_t)(mb + r) * N + n] = acc[i][j][r] + bv;
        }
    }
}

// ---------------- Fallback: round-1 fused kernel ----------------
__global__ __launch_bounds__(256, 2)
void q4gemm_fused(const float* __restrict__ A, const int* __restrict__ Q,
                  const float* __restrict__ S, const int* __restrict__ Zp,
                  const float* __restrict__ bias, float* __restrict__ C,
                  int M, int N, int K, int nb)
{
    __shared__ __align__(16) unsigned short As[BM * LDSN];
    __shared__ __align__(16) unsigned short Bs[BN * LDSN];

    const int tid = threadIdx.x;
    const int m0  = blockIdx.x * BM;
    const int n0  = blockIdx.y * BN;
    const int srow = tid >> 4;
    const int scol = (tid & 15) << 2;
    const int lane = tid & 63;
    const int wave = tid >> 6;
    const int wm   = (wave >> 1) * 64;
    const int wn   = (wave & 1) * 64;
    const int fr   = lane & 15;
    const int quad = lane >> 4;

    f32x4 acc[4][4];
    #pragma unroll
    for (int i = 0; i < 4; ++i)
        #pragma unroll
        for (int j = 0; j < 4; ++j)
            acc[i][j] = (f32x4){0.f, 0.f, 0.f, 0.f};

    const int ktiles = K / BK;
    for (int kt = 0; kt < ktiles; ++kt) {
        const int k0 = kt * BK;
        #pragma unroll
        for (int i = 0; i < 8; ++i) {
            const int r = i * 16 + srow;
            const float4 v = *(const float4*)(A + (size_t)(m0 + r) * K + k0 + scol);
            uint2 p; p.x = pack2(v.x, v.y); p.y = pack2(v.z, v.w);
            *(uint2*)&As[r * LDSN + scol] = p;
        }
        #pragma unroll
        for (int i = 0; i < 8; ++i) {
            const int r = i * 16 + srow;
            const int n = n0 + r;
            const int4 q = *(const int4*)(Q + (size_t)n * K + k0 + scol);
            const float s  = S[(size_t)n * nb + kt];
            const float zs = (float)Zp[(size_t)n * nb + kt] * s;
            uint2 p;
            p.x = pack2((float)q.x * s - zs, (float)q.y * s - zs);
            p.y = pack2((float)q.z * s - zs, (float)q.w * s - zs);
            *(uint2*)&Bs[r * LDSN + scol] = p;
        }
        __syncthreads();
        #pragma unroll
        for (int ks = 0; ks < 2; ++ks) {
            bf16x8 af[4], bfg[4];
            #pragma unroll
            for (int i = 0; i < 4; ++i)
                af[i] = *(const bf16x8*)&As[(wm + i * 16 + fr) * LDSN + ks * 32 + quad * 8];
            #pragma unroll
            for (int j = 0; j < 4; ++j)
                bfg[j] = *(const bf16x8*)&Bs[(wn + j * 16 + fr) * LDSN + ks * 32 + quad * 8];
            #pragma unroll
            for (int i = 0; i < 4; ++i)
                #pragma unroll
                for (int j = 0; j < 4; ++j)
                    acc[i][j] = __builtin_amdgcn_mfma_f32_16x16x32_bf16(af[i], bfg[j], acc[i][j], 0, 0, 0);
        }
        __syncthreads();
    }
    #pragma unroll
    for (int j = 0; j < 4; ++j) {
        const int n = n0 + wn + j * 16 + fr;
        const float bv = bias[n];
        #pragma unroll
        for (int i = 0; i < 4; ++i) {
            const int mb = m0 + wm + i * 16 + quad * 4;
            #pragma unroll
            for (int r = 0; r < 4; ++r)
                C[(size_t)(mb + r) * N + n] = acc[i][j][r] + bv;
        }
    }
}

extern "C" void kernel_launch(void* const* d_in, const int* in_sizes, int n_in,
                              void* d_out, int out_size, void* d_ws, size_t ws_size,
                              hipStream_t stream) {
    const float* A    = (const float*)d_in[0];
    const int*   Q    = (const int*)d_in[1];
    const float* S    = (const float*)d_in[2];
    const int*   Zp   = (const int*)d_in[3];
    const float* bias = (const float*)d_in[4];
    float* C = (float*)d_out;

    const int N  = in_sizes[4];
    const int K  = in_sizes[1] / N;
    const int M  = in_sizes[0] / K;
    const int nb = in_sizes[2] / N;

    const size_t needA = (size_t)M * K * 2;
    const size_t needW = (size_t)N * K * 2;

    if (ws_size >= needA + needW) {
        unsigned short* Ab = (unsigned short*)d_ws;
        unsigned short* Wb = (unsigned short*)((char*)d_ws + needA);

        long total4 = (long)M * K / 4;
        a2bf_kernel<<<(unsigned)((total4 + 255) / 256), 256, 0, stream>>>(A, Ab, total4);

        dim3 dq_grid((K / 8 + 255) / 256, N);
        dequant_kernel<<<dq_grid, 256, 0, stream>>>(Q, S, Zp, Wb, K, nb);

        if ((M % 256) == 0 && (N % 256) == 0 && (K % 128) == 0 && K >= 256) {
            dim3 grid(M / 256, N / 256);
            gemm8_kernel<<<grid, dim3(512), 0, stream>>>(Ab, Wb, bias, C, M, N, K);
        } else {
            dim3 grid(M / BM, N / BN);
            gemm_bt_kernel<<<grid, dim3(256), 0, stream>>>(Ab, Wb, bias, C, M, N, K);
        }
    } else {
        dim3 grid(M / BM, N / BN);
        q4gemm_fused<<<grid, dim3(256), 0, stream>>>(A, Q, S, Zp, bias, C, M, N, K, nb);
    }
}

// Round 2
// 658.502 us; speedup vs baseline: 1.1030x; 1.1030x over previous
//
#include <hip/hip_runtime.h>

// BlkQ4Linear: out[m,n] = sum_k in[m,k]*(q[n,k]-zp[n,k/64])*s[n,k/64] + bias[n]
// M=4096 K=4096 N=11008.
// Round 5: R4's 8-phase kernel stalled at 37% MfmaUtil (~1460 cyc/phase vs
// 620 MFMA floor). Theory: SIInsertWaitcnts sees compiler ds_reads aliasing
// outstanding global_load_lds DMAs to the same LDS arrays and pins them with
// conservative vmcnt waits -> pipeline depth collapses to ~1 phase. Fix:
// fragment reads become inline-asm ds_read_b128 (base VGPR + imm offset),
// barriers become raw asm s_barrier; only OUR counted vmcnt/lgkm waits remain
// in the loop. Plus: bijective XCD swizzle (688%8==0), merged pre-pass.
// Stage/vmcnt schedule identical to R4 (re-verified race-free).

#define BM 128
#define BN 128
#define BK 64
#define LDSN 72  // fused-fallback LDS pad

typedef __attribute__((ext_vector_type(8))) short bf16x8;
typedef __attribute__((ext_vector_type(4))) float f32x4;

__device__ __forceinline__ unsigned short f2bf(float f) {
    union { float f; unsigned int u; } v; v.f = f;
    unsigned int u = v.u;
    u += 0x7FFFu + ((u >> 16) & 1u);   // RNE
    return (unsigned short)(u >> 16);
}
__device__ __forceinline__ unsigned int pack2(float a, float b) {
    return (unsigned int)f2bf(a) | ((unsigned int)f2bf(b) << 16);
}

__device__ __forceinline__ void gl_lds16(const void* gp, void* lp) {
    __builtin_amdgcn_global_load_lds(
        (const __attribute__((address_space(1))) unsigned int*)gp,
        (__attribute__((address_space(3))) unsigned int*)lp,
        16, 0, 0);
}

__device__ __forceinline__ unsigned lds_off(const void* p) {
    return (unsigned)(unsigned long long)
        (const __attribute__((address_space(3))) void*)p;
}

template<int IMM>
__device__ __forceinline__ bf16x8 ds128(unsigned a) {
    bf16x8 d;
    asm volatile("ds_read_b128 %0, %1 offset:%2"
                 : "=v"(d) : "v"(a), "i"(IMM));
    return d;
}

// ---------------- Pass 1 (merged): A fp32->bf16 AND Q int32->bf16 W ----------
// gridDim.y = M + N: rows [0,M) convert A, rows [M,M+N) dequant W.
// 8 elems/thread, gridDim.x covers K/8 per 256-thread block.
__global__ __launch_bounds__(256)
void prep_kernel(const float* __restrict__ A, const int* __restrict__ Q,
                 const float* __restrict__ S, const int* __restrict__ Zp,
                 unsigned short* __restrict__ Ab, unsigned short* __restrict__ W,
                 int M, int K, int nb)
{
    const int y = blockIdx.y;
    const int k = (blockIdx.x * 256 + threadIdx.x) * 8;
    if (k >= K) return;
    if (y < M) {
        const float4* ap = (const float4*)(A + (size_t)y * K + k);
        float4 a0 = ap[0], a1 = ap[1];
        uint4 o;
        o.x = pack2(a0.x, a0.y); o.y = pack2(a0.z, a0.w);
        o.z = pack2(a1.x, a1.y); o.w = pack2(a1.z, a1.w);
        *(uint4*)(Ab + (size_t)y * K + k) = o;
    } else {
        const int n = y - M;
        const int kb = k >> 6;
        const float s  = S[(size_t)n * nb + kb];
        const float zs = (float)Zp[(size_t)n * nb + kb] * s;
        const int4* qp = (const int4*)(Q + (size_t)n * K + k);
        int4 q0 = qp[0], q1 = qp[1];
        uint4 o;
        o.x = pack2((float)q0.x * s - zs, (float)q0.y * s - zs);
        o.y = pack2((float)q0.z * s - zs, (float)q0.w * s - zs);
        o.z = pack2((float)q1.x * s - zs, (float)q1.y * s - zs);
        o.w = pack2((float)q1.z * s - zs, (float)q1.w * s - zs);
        *(uint4*)(W + (size_t)n * K + k) = o;
    }
}

// ---------------- Pass 2: 256x256 8-phase bf16 GEMM (asm-scheduled) ---------
// Waves 2(M) x 4(N); per-wave 128x64 C. Per phase: one 128x128 C-quadrant,
// 16 MFMA/wave. LDS As[2][256][64], Bs[2][256][64] (128 KiB), tile t->buf t&1.
// Swizzle: physical 16B chunk p of row r holds logical chunk p^(r&7); applied
// on the global source column at staging (LDS dst linear, HW reqt), inverted
// in the read address (ck0/ck1 below). Measured 0 bank-conflict cycles.

#define G8_BARRIER() asm volatile("s_barrier" ::: "memory")
#define G8_VMCNT(n)  asm volatile("s_waitcnt vmcnt(" #n ")" ::: "memory")
#define G8_LGKM0()   do { asm volatile("s_waitcnt lgkmcnt(0)" ::: "memory"); \
    __builtin_amdgcn_sched_barrier(0); } while (0)

#define G8_STAGE(G, kt, h, base, b)                                          \
  do {                                                                       \
    const unsigned short* _s = (G) + (long)(kt) * 64 + (long)(h) * 128 * K;  \
    gl_lds16(_s + aoff0, (base) + (b) * 32768 + (h) * 16384 + lds0);         \
    gl_lds16(_s + aoff1, (base) + (b) * 32768 + (h) * 16384 + lds1);         \
  } while (0)

// Fragment reads: pA0/pA1 (pB0/pB1) hold base LDS addrs incl. per-lane row
// and the swizzled chunk byte for ks=0 / ks=1. Buffer/half/frag-index are
// compile-time immediates (<= 55296, fits 16-bit offset field).
#define G8_LOAD_AF(b, mh)                                                    \
  af[0][0] = ds128<(b)*32768 + (mh)*16384 + 0*2048>(pA0);                    \
  af[1][0] = ds128<(b)*32768 + (mh)*16384 + 1*2048>(pA0);                    \
  af[2][0] = ds128<(b)*32768 + (mh)*16384 + 2*2048>(pA0);                    \
  af[3][0] = ds128<(b)*32768 + (mh)*16384 + 3*2048>(pA0);                    \
  af[0][1] = ds128<(b)*32768 + (mh)*16384 + 0*2048>(pA1);                    \
  af[1][1] = ds128<(b)*32768 + (mh)*16384 + 1*2048>(pA1);                    \
  af[2][1] = ds128<(b)*32768 + (mh)*16384 + 2*2048>(pA1);                    \
  af[3][1] = ds128<(b)*32768 + (mh)*16384 + 3*2048>(pA1);

#define G8_LOAD_BF(b, nh)                                                    \
  bfg[0][0] = ds128<(b)*32768 + (nh)*16384 + 0*2048>(pB0);                   \
  bfg[1][0] = ds128<(b)*32768 + (nh)*16384 + 1*2048>(pB0);                   \
  bfg[0][1] = ds128<(b)*32768 + (nh)*16384 + 0*2048>(pB1);                   \
  bfg[1][1] = ds128<(b)*32768 + (nh)*16384 + 1*2048>(pB1);

#define G8_MFMA(q)                                                           \
  __builtin_amdgcn_s_setprio(1);                                             \
  { _Pragma("unroll") for (int _i = 0; _i < 4; ++_i)                         \
    _Pragma("unroll") for (int _j = 0; _j < 2; ++_j) {                       \
      acc[q][_i][_j] = __builtin_amdgcn_mfma_f32_16x16x32_bf16(              \
          af[_i][0], bfg[_j][0], acc[q][_i][_j], 0, 0, 0);                   \
      acc[q][_i][_j] = __builtin_amdgcn_mfma_f32_16x16x32_bf16(              \
          af[_i][1], bfg[_j][1], acc[q][_i][_j], 0, 0, 0);                   \
  } }                                                                        \
  __builtin_amdgcn_s_setprio(0);

__global__ __launch_bounds__(512, 2)
void gemm8_kernel(const unsigned short* __restrict__ Ab,
                  const unsigned short* __restrict__ Wb,
                  const float* __restrict__ bias, float* __restrict__ C,
                  int M, int N, int K)
{
    __shared__ __align__(16) unsigned short As[2][256][64];
    __shared__ __align__(16) unsigned short Bs[2][256][64];

    const int tid  = threadIdx.x;

    // Bijective XCD-chunked swizzle (T1/m204), then M-fastest decode:
    // 16 consecutive same-XCD blocks share one B panel (L2 locality).
    const int nwg = gridDim.x;
    int wg = blockIdx.x;
    {
        const int q8 = nwg >> 3, r8 = nwg & 7, x = wg & 7, s = wg >> 3;
        wg = (x < r8 ? x * (q8 + 1) : r8 * (q8 + 1) + (x - r8) * q8) + s;
    }
    const int gx = M / 256;
    const int m0 = (wg % gx) * 256;
    const int n0 = (wg / gx) * 256;

    const int lane = tid & 63;
    const int wave = tid >> 6;
    const int ww   = wave >> 2;       // 0..1, m-dir
    const int wv   = wave & 3;        // 0..3, n-dir
    const int fr   = lane & 15;
    const int quad = lane >> 4;
    const int sw   = fr & 7;

    // staging constants: thread covers chunks tid and 512+tid of each half
    const int rl0 = tid >> 3;
    const int rl1 = (512 + tid) >> 3;
    const int pp  = tid & 7;
    const long aoff0 = (long)rl0 * K + (long)((pp ^ (rl0 & 7)) * 8);
    const long aoff1 = (long)rl1 * K + (long)((pp ^ (rl1 & 7)) * 8);
    const int lds0 = tid * 16;
    const int lds1 = (512 + tid) * 16;

    // fragment-read bases (inverse swizzle): logical chunk l=ks*4+quad at
    // physical byte ((l^sw)*16); row stride 128 B.
    const int ck0 = ((quad    ) ^ sw) * 16;
    const int ck1 = ((quad + 4) ^ sw) * 16;
    const int arow = ww * 64 + fr;
    const int brow = wv * 32 + fr;

    char* AsB = (char*)&As[0][0][0];
    char* BsB = (char*)&Bs[0][0][0];
    const unsigned pA0 = lds_off(AsB) + arow * 128 + ck0;
    const unsigned pA1 = lds_off(AsB) + arow * 128 + ck1;
    const unsigned pB0 = lds_off(BsB) + brow * 128 + ck0;
    const unsigned pB1 = lds_off(BsB) + brow * 128 + ck1;

    const unsigned short* Ag = Ab + (size_t)m0 * K;
    const unsigned short* Bg = Wb + (size_t)n0 * K;

    f32x4 acc[4][4][2];
    #pragma unroll
    for (int q = 0; q < 4; ++q)
        #pragma unroll
        for (int i = 0; i < 4; ++i)
            #pragma unroll
            for (int j = 0; j < 2; ++j)
                acc[q][i][j] = (f32x4){0.f, 0.f, 0.f, 0.f};

    bf16x8 af[4][2], bfg[2][2];

    // ---- prologue: tile0 (buf0) fully + A0,B0 of tile1 (buf1) ----
    G8_STAGE(Ag, 0, 0, AsB, 0);
    G8_STAGE(Bg, 0, 0, BsB, 0);
    G8_STAGE(Ag, 0, 1, AsB, 0);
    G8_STAGE(Bg, 0, 1, BsB, 0);
    G8_STAGE(Ag, 1, 0, AsB, 1);
    G8_STAGE(Bg, 1, 0, BsB, 1);
    G8_VMCNT(4);              // tile0's 8 loads landed; A0,B0(1) in flight
    G8_BARRIER();

    const int nit = K / 128;
    for (int it = 0; it < nit - 1; ++it) {
        const int t = 2 * it;
        // P1: buf0 q(0,0) | stage A1(t+1)->buf1 | vmcnt(6) lands A1,B1(t)
        G8_LOAD_AF(0, 0) G8_LOAD_BF(0, 0)
        G8_STAGE(Ag, t + 1, 1, AsB, 1);
        G8_BARRIER(); G8_LGKM0();
        G8_MFMA(0);
        G8_VMCNT(6);
        G8_BARRIER();
        // P2: buf0 q(0,1) | stage B1(t+1)->buf1
        G8_LOAD_BF(0, 1)
        G8_STAGE(Bg, t + 1, 1, BsB, 1);
        G8_BARRIER(); G8_LGKM0();
        G8_MFMA(1);
        G8_BARRIER();
        // P3: buf0 q(1,0) | stage A0(t+2)->buf0 (slot read at P1)
        G8_LOAD_AF(0, 1) G8_LOAD_BF(0, 0)
        G8_STAGE(Ag, t + 2, 0, AsB, 0);
        G8_BARRIER(); G8_LGKM0();
        G8_MFMA(2);
        G8_BARRIER();
        // P4: buf0 q(1,1) | stage B0(t+2)->buf0 | vmcnt(8) lands A0,B0(t+1)
        G8_LOAD_BF(0, 1)
        G8_STAGE(Bg, t + 2, 0, BsB, 0);
        G8_BARRIER(); G8_LGKM0();
        G8_MFMA(3);
        G8_VMCNT(8);
        G8_BARRIER();
        // P5: buf1 q(0,0) | stage A1(t+2)->buf0 | vmcnt(6) lands A1,B1(t+1)
        G8_LOAD_AF(1, 0) G8_LOAD_BF(1, 0)
        G8_STAGE(Ag, t + 2, 1, AsB, 0);
        G8_BARRIER(); G8_LGKM0();
        G8_MFMA(0);
        G8_VMCNT(6);
        G8_BARRIER();
        // P6: buf1 q(0,1) | stage B1(t+2)->buf0
        G8_LOAD_BF(1, 1)
        G8_STAGE(Bg, t + 2, 1, BsB, 0);
        G8_BARRIER(); G8_LGKM0();
        G8_MFMA(1);
        G8_BARRIER();
        // P7: buf1 q(1,0) | stage A0(t+3)->buf1
        G8_LOAD_AF(1, 1) G8_LOAD_BF(1, 0)
        G8_STAGE(Ag, t + 3, 0, AsB, 1);
        G8_BARRIER(); G8_LGKM0();
        G8_MFMA(2);
        G8_BARRIER();
        // P8: buf1 q(1,1) | stage B0(t+3)->buf1 | vmcnt(8) lands A0,B0(t+2)
        G8_LOAD_BF(1, 1)
        G8_STAGE(Bg, t + 3, 0, BsB, 1);
        G8_BARRIER(); G8_LGKM0();
        G8_MFMA(3);
        G8_VMCNT(8);
        G8_BARRIER();
    }
    // ---- peeled last iteration (tiles 2*nit-2, 2*nit-1): drain ----
    {
        const int t = 2 * (nit - 1);
        G8_LOAD_AF(0, 0) G8_LOAD_BF(0, 0)
        G8_STAGE(Ag, t + 1, 1, AsB, 1);
        G8_BARRIER(); G8_LGKM0(); G8_MFMA(0); G8_VMCNT(6); G8_BARRIER();

        G8_LOAD_BF(0, 1)
        G8_STAGE(Bg, t + 1, 1, BsB, 1);
        G8_BARRIER(); G8_LGKM0(); G8_MFMA(1); G8_BARRIER();

        G8_LOAD_AF(0, 1) G8_LOAD_BF(0, 0)
        G8_BARRIER(); G8_LGKM0(); G8_MFMA(2); G8_BARRIER();

        G8_LOAD_BF(0, 1)
        G8_BARRIER(); G8_LGKM0(); G8_MFMA(3); G8_VMCNT(4); G8_BARRIER();

        G8_LOAD_AF(1, 0) G8_LOAD_BF(1, 0)
        G8_BARRIER(); G8_LGKM0(); G8_MFMA(0); G8_VMCNT(0); G8_BARRIER();

        G8_LOAD_BF(1, 1)
        G8_BARRIER(); G8_LGKM0(); G8_MFMA(1); G8_BARRIER();

        G8_LOAD_AF(1, 1) G8_LOAD_BF(1, 0)
        G8_BARRIER(); G8_LGKM0(); G8_MFMA(2); G8_BARRIER();

        G8_LOAD_BF(1, 1)
        G8_BARRIER(); G8_LGKM0(); G8_MFMA(3); G8_BARRIER();
    }

    // ---- epilogue: D layout col = fr (n), row = quad*4 + r (m) ----
    #pragma unroll
    for (int q = 0; q < 4; ++q) {
        const int mh = q >> 1, nh = q & 1;
        #pragma unroll
        for (int j = 0; j < 2; ++j) {
            const int n = n0 + nh * 128 + brow + j * 16;
            const float bv = bias[n];
            #pragma unroll
            for (int i = 0; i < 4; ++i) {
                const int mb = m0 + mh * 128 + ww * 64 + i * 16 + quad * 4;
                #pragma unroll
                for (int r = 0; r < 4; ++r)
                    C[(size_t)(mb + r) * N + n] = acc[q][i][j][r] + bv;
            }
        }
    }
}

// ---------------- Pass 2 (fallback): 128x128 m97-structure GEMM -------------
__global__ __launch_bounds__(256, 2)
void gemm_bt_kernel(const unsigned short* __restrict__ Ab,
                    const unsigned short* __restrict__ Wb,
                    const float* __restrict__ bias, float* __restrict__ C,
                    int M, int N, int K)
{
    __shared__ __align__(16) unsigned short As[BM * BK];
    __shared__ __align__(16) unsigned short Bs[BN * BK];

    const int tid = threadIdx.x;
    const int m0  = blockIdx.x * BM;
    const int n0  = blockIdx.y * BN;

    const int lane = tid & 63;
    const int wave = tid >> 6;
    const int wm   = (wave >> 1) * 64;
    const int wn   = (wave & 1) * 64;
    const int fr   = lane & 15;
    const int quad = lane >> 4;
    const int sw   = fr & 7;

    f32x4 acc[4][4];
    #pragma unroll
    for (int i = 0; i < 4; ++i)
        #pragma unroll
        for (int j = 0; j < 4; ++j)
            acc[i][j] = (f32x4){0.f, 0.f, 0.f, 0.f};

    const int ktiles = K / BK;
    for (int kt = 0; kt < ktiles; ++kt) {
        const int k0 = kt * BK;
        #pragma unroll
        for (int i = 0; i < 4; ++i) {
            const int c    = i * 256 + tid;
            const int row  = c >> 3;
            const int g    = (c & 7) ^ (row & 7);
            const int cole = g * 8;
            gl_lds16(Ab + (size_t)(m0 + row) * K + k0 + cole, (char*)As + c * 16);
            gl_lds16(Wb + (size_t)(n0 + row) * K + k0 + cole, (char*)Bs + c * 16);
        }
        __syncthreads();

        #pragma unroll
        for (int ks = 0; ks < 2; ++ks) {
            bf16x8 af[4], bfg[4];
            #pragma unroll
            for (int i = 0; i < 4; ++i) {
                const int row = wm + i * 16 + fr;
                const int p   = (ks * 4 + quad) ^ sw;
                af[i] = *(const bf16x8*)&As[row * BK + p * 8];
            }
            #pragma unroll
            for (int j = 0; j < 4; ++j) {
                const int row = wn + j * 16 + fr;
                const int p   = (ks * 4 + quad) ^ sw;
                bfg[j] = *(const bf16x8*)&Bs[row * BK + p * 8];
            }
            #pragma unroll
            for (int i = 0; i < 4; ++i)
                #pragma unroll
                for (int j = 0; j < 4; ++j)
                    acc[i][j] = __builtin_amdgcn_mfma_f32_16x16x32_bf16(af[i], bfg[j], acc[i][j], 0, 0, 0);
        }
        __syncthreads();
    }

    #pragma unroll
    for (int j = 0; j < 4; ++j) {
        const int n = n0 + wn + j * 16 + fr;
        const float bv = bias[n];
        #pragma unroll
        for (int i = 0; i < 4; ++i) {
            const int mb = m0 + wm + i * 16 + quad * 4;
            #pragma unroll
            for (int r = 0; r < 4; ++r)
                C[(size_t)(mb + r) * N + n] = acc[i][j][r] + bv;
        }
    }
}

// ---------------- Fallback: round-1 fused kernel ----------------
__global__ __launch_bounds__(256, 2)
void q4gemm_fused(const float* __restrict__ A, const int* __restrict__ Q,
                  const float* __restrict__ S, const int* __restrict__ Zp,
                  const float* __restrict__ bias, float* __restrict__ C,
                  int M, int N, int K, int nb)
{
    __shared__ __align__(16) unsigned short As[BM * LDSN];
    __shared__ __align__(16) unsigned short Bs[BN * LDSN];

    const int tid = threadIdx.x;
    const int m0  = blockIdx.x * BM;
    const int n0  = blockIdx.y * BN;
    const int srow = tid >> 4;
    const int scol = (tid & 15) << 2;
    const int lane = tid & 63;
    const int wave = tid >> 6;
    const int wm   = (wave >> 1) * 64;
    const int wn   = (wave & 1) * 64;
    const int fr   = lane & 15;
    const int quad = lane >> 4;

    f32x4 acc[4][4];
    #pragma unroll
    for (int i = 0; i < 4; ++i)
        #pragma unroll
        for (int j = 0; j < 4; ++j)
            acc[i][j] = (f32x4){0.f, 0.f, 0.f, 0.f};

    const int ktiles = K / BK;
    for (int kt = 0; kt < ktiles; ++kt) {
        const int k0 = kt * BK;
        #pragma unroll
        for (int i = 0; i < 8; ++i) {
            const int r = i * 16 + srow;
            const float4 v = *(const float4*)(A + (size_t)(m0 + r) * K + k0 + scol);
            uint2 p; p.x = pack2(v.x, v.y); p.y = pack2(v.z, v.w);
            *(uint2*)&As[r * LDSN + scol] = p;
        }
        #pragma unroll
        for (int i = 0; i < 8; ++i) {
            const int r = i * 16 + srow;
            const int n = n0 + r;
            const int4 q = *(const int4*)(Q + (size_t)n * K + k0 + scol);
            const float s  = S[(size_t)n * nb + kt];
            const float zs = (float)Zp[(size_t)n * nb + kt] * s;
            uint2 p;
            p.x = pack2((float)q.x * s - zs, (float)q.y * s - zs);
            p.y = pack2((float)q.z * s - zs, (float)q.w * s - zs);
            *(uint2*)&Bs[r * LDSN + scol] = p;
        }
        __syncthreads();
        #pragma unroll
        for (int ks = 0; ks < 2; ++ks) {
            bf16x8 af[4], bfg[4];
            #pragma unroll
            for (int i = 0; i < 4; ++i)
                af[i] = *(const bf16x8*)&As[(wm + i * 16 + fr) * LDSN + ks * 32 + quad * 8];
            #pragma unroll
            for (int j = 0; j < 4; ++j)
                bfg[j] = *(const bf16x8*)&Bs[(wn + j * 16 + fr) * LDSN + ks * 32 + quad * 8];
            #pragma unroll
            for (int i = 0; i < 4; ++i)
                #pragma unroll
                for (int j = 0; j < 4; ++j)
                    acc[i][j] = __builtin_amdgcn_mfma_f32_16x16x32_bf16(af[i], bfg[j], acc[i][j], 0, 0, 0);
        }
        __syncthreads();
    }
    #pragma unroll
    for (int j = 0; j < 4; ++j) {
        const int n = n0 + wn + j * 16 + fr;
        const float bv = bias[n];
        #pragma unroll
        for (int i = 0; i < 4; ++i) {
            const int mb = m0 + wm + i * 16 + quad * 4;
            #pragma unroll
            for (int r = 0; r < 4; ++r)
                C[(size_t)(mb + r) * N + n] = acc[i][j][r] + bv;
        }
    }
}

extern "C" void kernel_launch(void* const* d_in, const int* in_sizes, int n_in,
                              void* d_out, int out_size, void* d_ws, size_t ws_size,
                              hipStream_t stream) {
    const float* A    = (const float*)d_in[0];
    const int*   Q    = (const int*)d_in[1];
    const float* S    = (const float*)d_in[2];
    const int*   Zp   = (const int*)d_in[3];
    const float* bias = (const float*)d_in[4];
    float* C = (float*)d_out;

    const int N  = in_sizes[4];
    const int K  = in_sizes[1] / N;
    const int M  = in_sizes[0] / K;
    const int nb = in_sizes[2] / N;

    const size_t needA = (size_t)M * K * 2;
    const size_t needW = (size_t)N * K * 2;

    if (ws_size >= needA + needW && (K % 2048) == 0) {
        unsigned short* Ab = (unsigned short*)d_ws;
        unsigned short* Wb = (unsigned short*)((char*)d_ws + needA);

        dim3 pgrid(K / 2048, M + N);
        prep_kernel<<<pgrid, 256, 0, stream>>>(A, Q, S, Zp, Ab, Wb, M, K, nb);

        if ((M % 256) == 0 && (N % 256) == 0 && (K % 128) == 0 && K >= 256) {
            gemm8_kernel<<<dim3((M / 256) * (N / 256)), dim3(512), 0, stream>>>(
                Ab, Wb, bias, C, M, N, K);
        } else {
            dim3 grid(M / BM, N / BN);
            gemm_bt_kernel<<<grid, dim3(256), 0, stream>>>(Ab, Wb, bias, C, M, N, K);
        }
    } else {
        dim3 grid(M / BM, N / BN);
        q4gemm_fused<<<grid, dim3(256), 0, stream>>>(A, Q, S, Zp, bias, C, M, N, K, nb);
    }
}

// Round 4
// 654.173 us; speedup vs baseline: 1.1103x; 1.0066x over previous
//
#include <hip/hip_runtime.h>

// BlkQ4Linear: out[m,n] = sum_k in[m,k]*(q[n,k]-zp[n,k/64])*s[n,k/64] + bias[n]
// M=4096 K=4096 N=11008.
// Round 7: revert R6's failed 32x32 shape switch; back to the VERIFIED R5
// 8-phase 16x16x32 kernel (378 us, passed). Apply R6's one sound idea in
// minimal form: keep BOTH B fragment sets register-resident (bf0/bf1) so
// P3/P4 stop re-reading B from LDS. ds_read per wave per K-tile: 32 -> 24
// (-25% LDS read traffic; R5 measured ~99 B/cyc/CU ds_read = at the LDS
// ceiling with MfmaUtil only 43.7% -> LDS-read-BW-bound). Everything else
// (stage placement, vmcnt ledger, swizzle, epilogue) is byte-identical to
// R5; new reads are a strict subset of R5's per phase.

#define BM 128
#define BN 128
#define BK 64
#define LDSN 72  // fused-fallback LDS pad

typedef __attribute__((ext_vector_type(8))) short bf16x8;
typedef __attribute__((ext_vector_type(4))) float f32x4;

__device__ __forceinline__ unsigned short f2bf(float f) {
    union { float f; unsigned int u; } v; v.f = f;
    unsigned int u = v.u;
    u += 0x7FFFu + ((u >> 16) & 1u);   // RNE
    return (unsigned short)(u >> 16);
}
__device__ __forceinline__ unsigned int pack2(float a, float b) {
    return (unsigned int)f2bf(a) | ((unsigned int)f2bf(b) << 16);
}

__device__ __forceinline__ void gl_lds16(const void* gp, void* lp) {
    __builtin_amdgcn_global_load_lds(
        (const __attribute__((address_space(1))) unsigned int*)gp,
        (__attribute__((address_space(3))) unsigned int*)lp,
        16, 0, 0);
}

__device__ __forceinline__ unsigned lds_off(const void* p) {
    return (unsigned)(unsigned long long)
        (const __attribute__((address_space(3))) void*)p;
}

template<int IMM>
__device__ __forceinline__ bf16x8 ds128(unsigned a) {
    bf16x8 d;
    asm volatile("ds_read_b128 %0, %1 offset:%2"
                 : "=v"(d) : "v"(a), "i"(IMM));
    return d;
}

// ---------------- Pass 1 (merged): A fp32->bf16 AND Q int32->bf16 W ----------
__global__ __launch_bounds__(256)
void prep_kernel(const float* __restrict__ A, const int* __restrict__ Q,
                 const float* __restrict__ S, const int* __restrict__ Zp,
                 unsigned short* __restrict__ Ab, unsigned short* __restrict__ W,
                 int M, int K, int nb)
{
    const int y = blockIdx.y;
    const int k = (blockIdx.x * 256 + threadIdx.x) * 8;
    if (k >= K) return;
    if (y < M) {
        const float4* ap = (const float4*)(A + (size_t)y * K + k);
        float4 a0 = ap[0], a1 = ap[1];
        uint4 o;
        o.x = pack2(a0.x, a0.y); o.y = pack2(a0.z, a0.w);
        o.z = pack2(a1.x, a1.y); o.w = pack2(a1.z, a1.w);
        *(uint4*)(Ab + (size_t)y * K + k) = o;
    } else {
        const int n = y - M;
        const int kb = k >> 6;
        const float s  = S[(size_t)n * nb + kb];
        const float zs = (float)Zp[(size_t)n * nb + kb] * s;
        const int4* qp = (const int4*)(Q + (size_t)n * K + k);
        int4 q0 = qp[0], q1 = qp[1];
        uint4 o;
        o.x = pack2((float)q0.x * s - zs, (float)q0.y * s - zs);
        o.y = pack2((float)q0.z * s - zs, (float)q0.w * s - zs);
        o.z = pack2((float)q1.x * s - zs, (float)q1.y * s - zs);
        o.w = pack2((float)q1.z * s - zs, (float)q1.w * s - zs);
        *(uint4*)(W + (size_t)n * K + k) = o;
    }
}

// ---------------- Pass 2: 256x256 8-phase bf16 GEMM (asm-scheduled) ---------
// Waves 2(M) x 4(N); per-wave 128x64 C. Per phase one 128x128 C-quadrant,
// 16 MFMA/wave. LDS As[2][256][64], Bs[2][256][64] (128 KiB), tile t->buf t&1.
// Swizzle: physical 16B chunk p of row r holds logical chunk p^(r&7); applied
// on the global source column at staging (LDS dst linear, HW reqt), inverted
// in the read address. Measured 0 bank-conflict cycles.
// Read pattern per K-tile (NEW): P1: 8 A + 4 B(nh0) | P2: 4 B(nh1) |
// P3: 8 A (bf0 register-resident) | P4: 0 (af, bf1 resident). 24 reads.

#define G8_BARRIER() asm volatile("s_barrier" ::: "memory")
#define G8_VMCNT(n)  asm volatile("s_waitcnt vmcnt(" #n ")" ::: "memory")
#define G8_LGKMC(n)  asm volatile("s_waitcnt lgkmcnt(" #n ")" ::: "memory")
#define G8_LGKM0()   do { asm volatile("s_waitcnt lgkmcnt(0)" ::: "memory"); \
    __builtin_amdgcn_sched_barrier(0); } while (0)

#define G8_STAGE(G, kt, h, base, b)                                          \
  do {                                                                       \
    const unsigned short* _s = (G) + (long)(kt) * 64 + (long)(h) * 128 * K;  \
    gl_lds16(_s + aoff0, (base) + (b) * 32768 + (h) * 16384 + lds0);         \
    gl_lds16(_s + aoff1, (base) + (b) * 32768 + (h) * 16384 + lds1);         \
  } while (0)

#define G8_LOAD_AF(b, mh)                                                    \
  af[0][0] = ds128<(b)*32768 + (mh)*16384 + 0*2048>(pA0);                    \
  af[1][0] = ds128<(b)*32768 + (mh)*16384 + 1*2048>(pA0);                    \
  af[2][0] = ds128<(b)*32768 + (mh)*16384 + 2*2048>(pA0);                    \
  af[3][0] = ds128<(b)*32768 + (mh)*16384 + 3*2048>(pA0);                    \
  af[0][1] = ds128<(b)*32768 + (mh)*16384 + 0*2048>(pA1);                    \
  af[1][1] = ds128<(b)*32768 + (mh)*16384 + 1*2048>(pA1);                    \
  af[2][1] = ds128<(b)*32768 + (mh)*16384 + 2*2048>(pA1);                    \
  af[3][1] = ds128<(b)*32768 + (mh)*16384 + 3*2048>(pA1);

#define G8_LOAD_BF(b, nh, BF)                                                \
  BF[0][0] = ds128<(b)*32768 + (nh)*16384 + 0*2048>(pB0);                    \
  BF[1][0] = ds128<(b)*32768 + (nh)*16384 + 1*2048>(pB0);                    \
  BF[0][1] = ds128<(b)*32768 + (nh)*16384 + 0*2048>(pB1);                    \
  BF[1][1] = ds128<(b)*32768 + (nh)*16384 + 1*2048>(pB1);

#define G8_MFMA(q, BF)                                                       \
  __builtin_amdgcn_s_setprio(1);                                             \
  { _Pragma("unroll") for (int _i = 0; _i < 4; ++_i)                         \
    _Pragma("unroll") for (int _j = 0; _j < 2; ++_j) {                       \
      acc[q][_i][_j] = __builtin_amdgcn_mfma_f32_16x16x32_bf16(              \
          af[_i][0], BF[_j][0], acc[q][_i][_j], 0, 0, 0);                    \
      acc[q][_i][_j] = __builtin_amdgcn_mfma_f32_16x16x32_bf16(              \
          af[_i][1], BF[_j][1], acc[q][_i][_j], 0, 0, 0);                    \
  } }                                                                        \
  __builtin_amdgcn_s_setprio(0);

__global__ __launch_bounds__(512, 2)
void gemm8_kernel(const unsigned short* __restrict__ Ab,
                  const unsigned short* __restrict__ Wb,
                  const float* __restrict__ bias, float* __restrict__ C,
                  int M, int N, int K)
{
    __shared__ __align__(16) unsigned short As[2][256][64];
    __shared__ __align__(16) unsigned short Bs[2][256][64];

    const int tid  = threadIdx.x;

    // Bijective XCD-chunked swizzle (T1/m204), M-fastest decode.
    const int nwg = gridDim.x;
    int wg = blockIdx.x;
    {
        const int q8 = nwg >> 3, r8 = nwg & 7, x = wg & 7, s = wg >> 3;
        wg = (x < r8 ? x * (q8 + 1) : r8 * (q8 + 1) + (x - r8) * q8) + s;
    }
    const int gx = M / 256;
    const int m0 = (wg % gx) * 256;
    const int n0 = (wg / gx) * 256;

    const int lane = tid & 63;
    const int wave = tid >> 6;
    const int ww   = wave >> 2;       // 0..1, m-dir
    const int wv   = wave & 3;        // 0..3, n-dir
    const int fr   = lane & 15;
    const int quad = lane >> 4;
    const int sw   = fr & 7;

    // staging constants: thread covers chunks tid and 512+tid of each half
    const int rl0 = tid >> 3;
    const int rl1 = (512 + tid) >> 3;
    const int pp  = tid & 7;
    const long aoff0 = (long)rl0 * K + (long)((pp ^ (rl0 & 7)) * 8);
    const long aoff1 = (long)rl1 * K + (long)((pp ^ (rl1 & 7)) * 8);
    const int lds0 = tid * 16;
    const int lds1 = (512 + tid) * 16;

    // fragment-read bases: logical chunk l=ks*4+quad at physical (l^sw)*16
    const int ck0 = ((quad    ) ^ sw) * 16;
    const int ck1 = ((quad + 4) ^ sw) * 16;
    const int arow = ww * 64 + fr;
    const int brow = wv * 32 + fr;

    char* AsB = (char*)&As[0][0][0];
    char* BsB = (char*)&Bs[0][0][0];
    const unsigned pA0 = lds_off(AsB) + arow * 128 + ck0;
    const unsigned pA1 = lds_off(AsB) + arow * 128 + ck1;
    const unsigned pB0 = lds_off(BsB) + brow * 128 + ck0;
    const unsigned pB1 = lds_off(BsB) + brow * 128 + ck1;

    const unsigned short* Ag = Ab + (size_t)m0 * K;
    const unsigned short* Bg = Wb + (size_t)n0 * K;

    f32x4 acc[4][4][2];
    #pragma unroll
    for (int q = 0; q < 4; ++q)
        #pragma unroll
        for (int i = 0; i < 4; ++i)
            #pragma unroll
            for (int j = 0; j < 2; ++j)
                acc[q][i][j] = (f32x4){0.f, 0.f, 0.f, 0.f};

    bf16x8 af[4][2], bf0[2][2], bf1[2][2];

    // ---- prologue: tile0 (buf0) fully + A0,B0 of tile1 (buf1) ----
    G8_STAGE(Ag, 0, 0, AsB, 0);
    G8_STAGE(Bg, 0, 0, BsB, 0);
    G8_STAGE(Ag, 0, 1, AsB, 0);
    G8_STAGE(Bg, 0, 1, BsB, 0);
    G8_STAGE(Ag, 1, 0, AsB, 1);
    G8_STAGE(Bg, 1, 0, BsB, 1);
    G8_VMCNT(4);              // tile0's 8 loads landed; A0,B0(1) in flight
    G8_BARRIER();

    const int nit = K / 128;
    for (int it = 0; it < nit - 1; ++it) {
        const int t = 2 * it;
        // P1: q(0,0) buf0 | 12 reads | stage A1(t+1)->buf1 | vmcnt(6)
        G8_LOAD_AF(0, 0) G8_LOAD_BF(0, 0, bf0)
        G8_STAGE(Ag, t + 1, 1, AsB, 1);
        G8_LGKMC(8);
        G8_BARRIER(); G8_LGKM0();
        G8_MFMA(0, bf0);
        G8_VMCNT(6);           // lands A1,B1(t) for P2/P3
        G8_BARRIER();
        // P2: q(0,1) buf0 | 4 reads | stage B1(t+1)->buf1
        G8_LOAD_BF(0, 1, bf1)
        G8_STAGE(Bg, t + 1, 1, BsB, 1);
        G8_BARRIER(); G8_LGKM0();
        G8_MFMA(1, bf1);
        G8_BARRIER();
        // P3: q(1,0) buf0 | 8 reads (bf0 resident) | stage A0(t+2)->buf0
        G8_LOAD_AF(0, 1)
        G8_STAGE(Ag, t + 2, 0, AsB, 0);
        G8_BARRIER(); G8_LGKM0();
        G8_MFMA(2, bf0);
        G8_BARRIER();
        // P4: q(1,1) buf0 | 0 reads (af, bf1 resident) | stage B0(t+2)->buf0
        G8_STAGE(Bg, t + 2, 0, BsB, 0);
        G8_BARRIER();
        G8_MFMA(3, bf1);
        G8_VMCNT(8);           // lands A0,B0(t+1) for P5
        G8_BARRIER();
        // P5: q(0,0) buf1 | 12 reads | stage A1(t+2)->buf0 | vmcnt(6)
        G8_LOAD_AF(1, 0) G8_LOAD_BF(1, 0, bf0)
        G8_STAGE(Ag, t + 2, 1, AsB, 0);
        G8_LGKMC(8);
        G8_BARRIER(); G8_LGKM0();
        G8_MFMA(0, bf0);
        G8_VMCNT(6);           // lands A1,B1(t+1) for P6/P7
        G8_BARRIER();
        // P6: q(0,1) buf1 | 4 reads | stage B1(t+2)->buf0
        G8_LOAD_BF(1, 1, bf1)
        G8_STAGE(Bg, t + 2, 1, BsB, 0);
        G8_BARRIER(); G8_LGKM0();
        G8_MFMA(1, bf1);
        G8_BARRIER();
        // P7: q(1,0) buf1 | 8 reads | stage A0(t+3)->buf1
        G8_LOAD_AF(1, 1)
        G8_STAGE(Ag, t + 3, 0, AsB, 1);
        G8_BARRIER(); G8_LGKM0();
        G8_MFMA(2, bf0);
        G8_BARRIER();
        // P8: q(1,1) buf1 | 0 reads | stage B0(t+3)->buf1 | vmcnt(8)
        G8_STAGE(Bg, t + 3, 0, BsB, 1);
        G8_BARRIER();
        G8_MFMA(3, bf1);
        G8_VMCNT(8);           // lands A0,B0(t+2) for next P1
        G8_BARRIER();
    }
    // ---- peeled last iteration (tiles 2*nit-2, 2*nit-1): drain ----
    {
        G8_LOAD_AF(0, 0) G8_LOAD_BF(0, 0, bf0)
        G8_STAGE(Ag, 2 * nit - 1, 1, AsB, 1);
        G8_LGKMC(8);
        G8_BARRIER(); G8_LGKM0(); G8_MFMA(0, bf0); G8_VMCNT(6); G8_BARRIER();

        G8_LOAD_BF(0, 1, bf1)
        G8_STAGE(Bg, 2 * nit - 1, 1, BsB, 1);
        G8_BARRIER(); G8_LGKM0(); G8_MFMA(1, bf1); G8_BARRIER();

        G8_LOAD_AF(0, 1)
        G8_BARRIER(); G8_LGKM0(); G8_MFMA(2, bf0); G8_BARRIER();

        G8_BARRIER(); G8_MFMA(3, bf1); G8_VMCNT(4); G8_BARRIER();

        G8_LOAD_AF(1, 0) G8_LOAD_BF(1, 0, bf0)
        G8_BARRIER(); G8_LGKM0(); G8_MFMA(0, bf0); G8_VMCNT(0); G8_BARRIER();

        G8_LOAD_BF(1, 1, bf1)
        G8_BARRIER(); G8_LGKM0(); G8_MFMA(1, bf1); G8_BARRIER();

        G8_LOAD_AF(1, 1)
        G8_BARRIER(); G8_LGKM0(); G8_MFMA(2, bf0); G8_BARRIER();

        G8_MFMA(3, bf1);
    }

    // ---- epilogue: D layout col = fr (n), row = quad*4 + r (m) ----
    #pragma unroll
    for (int q = 0; q < 4; ++q) {
        const int mh = q >> 1, nh = q & 1;
        #pragma unroll
        for (int j = 0; j < 2; ++j) {
            const int n = n0 + nh * 128 + brow + j * 16;
            const float bv = bias[n];
            #pragma unroll
            for (int i = 0; i < 4; ++i) {
                const int mb = m0 + mh * 128 + ww * 64 + i * 16 + quad * 4;
                #pragma unroll
                for (int r = 0; r < 4; ++r)
                    C[(size_t)(mb + r) * N + n] = acc[q][i][j][r] + bv;
            }
        }
    }
}

// ---------------- Pass 2 (fallback): 128x128 m97-structure GEMM -------------
__global__ __launch_bounds__(256, 2)
void gemm_bt_kernel(const unsigned short* __restrict__ Ab,
                    const unsigned short* __restrict__ Wb,
                    const float* __restrict__ bias, float* __restrict__ C,
                    int M, int N, int K)
{
    __shared__ __align__(16) unsigned short As[BM * BK];
    __shared__ __align__(16) unsigned short Bs[BN * BK];

    const int tid = threadIdx.x;
    const int m0  = blockIdx.x * BM;
    const int n0  = blockIdx.y * BN;

    const int lane = tid & 63;
    const int wave = tid >> 6;
    const int wm   = (wave >> 1) * 64;
    const int wn   = (wave & 1) * 64;
    const int fr   = lane & 15;
    const int quad = lane >> 4;
    const int sw   = fr & 7;

    f32x4 acc[4][4];
    #pragma unroll
    for (int i = 0; i < 4; ++i)
        #pragma unroll
        for (int j = 0; j < 4; ++j)
            acc[i][j] = (f32x4){0.f, 0.f, 0.f, 0.f};

    const int ktiles = K / BK;
    for (int kt = 0; kt < ktiles; ++kt) {
        const int k0 = kt * BK;
        #pragma unroll
        for (int i = 0; i < 4; ++i) {
            const int c    = i * 256 + tid;
            const int row  = c >> 3;
            const int g    = (c & 7) ^ (row & 7);
            const int cole = g * 8;
            gl_lds16(Ab + (size_t)(m0 + row) * K + k0 + cole, (char*)As + c * 16);
            gl_lds16(Wb + (size_t)(n0 + row) * K + k0 + cole, (char*)Bs + c * 16);
        }
        __syncthreads();

        #pragma unroll
        for (int ks = 0; ks < 2; ++ks) {
            bf16x8 af[4], bfg[4];
            #pragma unroll
            for (int i = 0; i < 4; ++i) {
                const int row = wm + i * 16 + fr;
                const int p   = (ks * 4 + quad) ^ sw;
                af[i] = *(const bf16x8*)&As[row * BK + p * 8];
            }
            #pragma unroll
            for (int j = 0; j < 4; ++j) {
                const int row = wn + j * 16 + fr;
                const int p   = (ks * 4 + quad) ^ sw;
                bfg[j] = *(const bf16x8*)&Bs[row * BK + p * 8];
            }
            #pragma unroll
            for (int i = 0; i < 4; ++i)
                #pragma unroll
                for (int j = 0; j < 4; ++j)
                    acc[i][j] = __builtin_amdgcn_mfma_f32_16x16x32_bf16(af[i], bfg[j], acc[i][j], 0, 0, 0);
        }
        __syncthreads();
    }

    #pragma unroll
    for (int j = 0; j < 4; ++j) {
        const int n = n0 + wn + j * 16 + fr;
        const float bv = bias[n];
        #pragma unroll
        for (int i = 0; i < 4; ++i) {
            const int mb = m0 + wm + i * 16 + quad * 4;
            #pragma unroll
            for (int r = 0; r < 4; ++r)
                C[(size_t)(mb + r) * N + n] = acc[i][j][r] + bv;
        }
    }
}

// ---------------- Fallback: round-1 fused kernel ----------------
__global__ __launch_bounds__(256, 2)
void q4gemm_fused(const float* __restrict__ A, const int* __restrict__ Q,
                  const float* __restrict__ S, const int* __restrict__ Zp,
                  const float* __restrict__ bias, float* __restrict__ C,
                  int M, int N, int K, int nb)
{
    __shared__ __align__(16) unsigned short As[BM * LDSN];
    __shared__ __align__(16) unsigned short Bs[BN * LDSN];

    const int tid = threadIdx.x;
    const int m0  = blockIdx.x * BM;
    const int n0  = blockIdx.y * BN;
    const int srow = tid >> 4;
    const int scol = (tid & 15) << 2;
    const int lane = tid & 63;
    const int wave = tid >> 6;
    const int wm   = (wave >> 1) * 64;
    const int wn   = (wave & 1) * 64;
    const int fr   = lane & 15;
    const int quad = lane >> 4;

    f32x4 acc[4][4];
    #pragma unroll
    for (int i = 0; i < 4; ++i)
        #pragma unroll
        for (int j = 0; j < 4; ++j)
            acc[i][j] = (f32x4){0.f, 0.f, 0.f, 0.f};

    const int ktiles = K / BK;
    for (int kt = 0; kt < ktiles; ++kt) {
        const int k0 = kt * BK;
        #pragma unroll
        for (int i = 0; i < 8; ++i) {
            const int r = i * 16 + srow;
            const float4 v = *(const float4*)(A + (size_t)(m0 + r) * K + k0 + scol);
            uint2 p; p.x = pack2(v.x, v.y); p.y = pack2(v.z, v.w);
            *(uint2*)&As[r * LDSN + scol] = p;
        }
        #pragma unroll
        for (int i = 0; i < 8; ++i) {
            const int r = i * 16 + srow;
            const int n = n0 + r;
            const int4 q = *(const int4*)(Q + (size_t)n * K + k0 + scol);
            const float s  = S[(size_t)n * nb + kt];
            const float zs = (float)Zp[(size_t)n * nb + kt] * s;
            uint2 p;
            p.x = pack2((float)q.x * s - zs, (float)q.y * s - zs);
            p.y = pack2((float)q.z * s - zs, (float)q.w * s - zs);
            *(uint2*)&Bs[r * LDSN + scol] = p;
        }
        __syncthreads();
        #pragma unroll
        for (int ks = 0; ks < 2; ++ks) {
            bf16x8 af[4], bfg[4];
            #pragma unroll
            for (int i = 0; i < 4; ++i)
                af[i] = *(const bf16x8*)&As[(wm + i * 16 + fr) * LDSN + ks * 32 + quad * 8];
            #pragma unroll
            for (int j = 0; j < 4; ++j)
                bfg[j] = *(const bf16x8*)&Bs[(wn + j * 16 + fr) * LDSN + ks * 32 + quad * 8];
            #pragma unroll
            for (int i = 0; i < 4; ++i)
                #pragma unroll
                for (int j = 0; j < 4; ++j)
                    acc[i][j] = __builtin_amdgcn_mfma_f32_16x16x32_bf16(af[i], bfg[j], acc[i][j], 0, 0, 0);
        }
        __syncthreads();
    }
    #pragma unroll
    for (int j = 0; j < 4; ++j) {
        const int n = n0 + wn + j * 16 + fr;
        const float bv = bias[n];
        #pragma unroll
        for (int i = 0; i < 4; ++i) {
            const int mb = m0 + wm + i * 16 + quad * 4;
            #pragma unroll
            for (int r = 0; r < 4; ++r)
                C[(size_t)(mb + r) * N + n] = acc[i][j][r] + bv;
        }
    }
}

extern "C" void kernel_launch(void* const* d_in, const int* in_sizes, int n_in,
                              void* d_out, int out_size, void* d_ws, size_t ws_size,
                              hipStream_t stream) {
    const float* A    = (const float*)d_in[0];
    const int*   Q    = (const int*)d_in[1];
    const float* S    = (const float*)d_in[2];
    const int*   Zp   = (const int*)d_in[3];
    const float* bias = (const float*)d_in[4];
    float* C = (float*)d_out;

    const int N  = in_sizes[4];
    const int K  = in_sizes[1] / N;
    const int M  = in_sizes[0] / K;
    const int nb = in_sizes[2] / N;

    const size_t needA = (size_t)M * K * 2;
    const size_t needW = (size_t)N * K * 2;

    if (ws_size >= needA + needW && (K % 2048) == 0) {
        unsigned short* Ab = (unsigned short*)d_ws;
        unsigned short* Wb = (unsigned short*)((char*)d_ws + needA);

        dim3 pgrid(K / 2048, M + N);
        prep_kernel<<<pgrid, 256, 0, stream>>>(A, Q, S, Zp, Ab, Wb, M, K, nb);

        if ((M % 256) == 0 && (N % 256) == 0 && (K % 128) == 0 && K >= 256) {
            gemm8_kernel<<<dim3((M / 256) * (N / 256)), dim3(512), 0, stream>>>(
                Ab, Wb, bias, C, M, N, K);
        } else {
            dim3 grid(M / BM, N / BN);
            gemm_bt_kernel<<<grid, dim3(256), 0, stream>>>(Ab, Wb, bias, C, M, N, K);
        }
    } else {
        dim3 grid(M / BM, N / BN);
        q4gemm_fused<<<grid, dim3(256), 0, stream>>>(A, Q, S, Zp, bias, C, M, N, K, nb);
    }
}